// Round 7
// baseline (6655.375 us; speedup 1.0000x reference)
//
#include <hip/hip_runtime.h>
#include <hip/hip_bf16.h>

#define TT 2048
#define HH 1024
#define GH 4096

__device__ __forceinline__ float sigm(float x){ return 1.0f / (1.0f + __expf(-x)); }

// -------- Phase 1: plain fp32 tiled GEMM (validated r3-r6) --------
// gx[t][j] = sum_k emb[tok[t]][k] * Wih[j][k] + bih[j] + bhh[j]
#define BM 128
#define BN 64
#define BK 32

__global__ __launch_bounds__(256) void gemm_simple(
    const int* __restrict__ tokens,
    const float* __restrict__ emb,
    const float* __restrict__ Wih,
    const float* __restrict__ bih,
    const float* __restrict__ bhh,
    float* __restrict__ gx)
{
  __shared__ float As[BM][BK+1];
  __shared__ float Bs[BN][BK+1];
  __shared__ int tok_s[BM];

  const int tid = threadIdx.x;
  const int bn = blockIdx.x;      // 0..63
  const int bm = blockIdx.y;      // 0..15
  const int m0 = bm*BM, n0 = bn*BN;

  if (tid < BM) tok_s[tid] = tokens[m0 + tid];
  __syncthreads();

  const int tm = tid >> 4;
  const int tn = tid & 15;

  float acc[8][4];
  #pragma unroll
  for (int i = 0; i < 8; ++i)
    #pragma unroll
    for (int j = 0; j < 4; ++j) acc[i][j] = 0.0f;

  for (int k0 = 0; k0 < HH; k0 += BK) {
    for (int idx = tid; idx < BM*BK; idx += 256) {
      int r = idx >> 5, c = idx & 31;
      As[r][c] = emb[(size_t)tok_s[r]*HH + k0 + c];
    }
    for (int idx = tid; idx < BN*BK; idx += 256) {
      int r = idx >> 5, c = idx & 31;
      Bs[r][c] = Wih[(size_t)(n0 + r)*HH + k0 + c];
    }
    __syncthreads();
    #pragma unroll
    for (int k = 0; k < BK; ++k) {
      float a[8], b[4];
      #pragma unroll
      for (int i = 0; i < 8; ++i) a[i] = As[tm*8 + i][k];
      #pragma unroll
      for (int j = 0; j < 4; ++j) b[j] = Bs[tn*4 + j][k];
      #pragma unroll
      for (int i = 0; i < 8; ++i)
        #pragma unroll
        for (int j = 0; j < 4; ++j)
          acc[i][j] = fmaf(a[i], b[j], acc[i][j]);
    }
    __syncthreads();
  }

  float bias[4];
  #pragma unroll
  for (int j = 0; j < 4; ++j) {
    int col = n0 + tn*4 + j;
    bias[j] = bih[col] + bhh[col];
  }
  #pragma unroll
  for (int i = 0; i < 8; ++i) {
    int r = m0 + tm*8 + i;
    #pragma unroll
    for (int j = 0; j < 4; ++j)
      gx[(size_t)r*GH + (n0 + tn*4 + j)] = acc[i][j] + bias[j];
  }
}

// -------- Phase 2: persistent scan (protocol validated ≡ stream-ordered, r3==r4) --------
// Block b owns h[b*16 .. b*16+16); 64 W_hh rows (4 gates x 16) in VGPRs (fp32).
// Per step: publish h via self-tagged u64 slots {tag=t | fp32 h}, ping-pong parity.
#define GBLK 64
#define NTH 512
#define HSTRIDE 130

__global__ __launch_bounds__(NTH, 2) void lstm_scan(
    const float* __restrict__ gx,
    const float* __restrict__ Whh,
    unsigned long long* slots,     // [2][1024]
    float* __restrict__ out)       // [2048] fp32 = h ; c   *** THE FIX ***
{
  const int b = blockIdx.x;
  const int tid = threadIdx.x;
  const int s  = tid & 31;   // 32 col-segments of 32 cols
  const int rg = tid >> 5;   // 16 row-groups of 4 rows

  __shared__ float h_lds[32*HSTRIDE];
  __shared__ float gates_lds[64];

  // rows rg*4+a (a=0..3): jrow = gate*1024 + b*16 + local; cols [s*32, s*32+32)
  float w[128];
  #pragma unroll
  for (int a = 0; a < 4; ++a) {
    int row = rg*4 + a;
    int jrow = ((row >> 4) << 10) + (b << 4) + (row & 15);
    const float* wr = Whh + (size_t)jrow*HH + s*32;
    #pragma unroll
    for (int q = 0; q < 8; ++q) {
      float4 f4 = ((const float4*)wr)[q];
      w[a*32 + q*4 + 0] = f4.x; w[a*32 + q*4 + 1] = f4.y;
      w[a*32 + q*4 + 2] = f4.z; w[a*32 + q*4 + 3] = f4.w;
    }
  }

  for (int i = tid; i < 32*HSTRIDE; i += NTH) h_lds[i] = 0.0f;   // h0 = 0
  float c0 = 0.0f, c1 = 0.0f;                                    // c state (tid<8)
  const int i0 = tid, i1 = tid + 512;
  const int p0 = (i0 >> 5)*HSTRIDE + (i0 & 31);
  const int p1 = (i1 >> 5)*HSTRIDE + (i1 & 31);
  const int myrow = rg*4 + s;                                    // valid for s<4
  const int myj = ((myrow >> 4) << 10) + (b << 4) + (myrow & 15);
  __syncthreads();

  for (int t = 0; t < TT; ++t) {
    float gxv = 0.0f;
    if (s < 4) gxv = gx[(size_t)t*GH + myj];     // prefetch; lands during poll

    if (t > 0) {
      const unsigned long long* sb = slots + (size_t)(t & 1)*1024;
      const unsigned tg = (unsigned)t;
      unsigned long long v0 = __hip_atomic_load(&sb[i0], __ATOMIC_RELAXED, __HIP_MEMORY_SCOPE_AGENT);
      unsigned long long v1 = __hip_atomic_load(&sb[i1], __ATOMIC_RELAXED, __HIP_MEMORY_SCOPE_AGENT);
      while ((unsigned)(v0 >> 32) != tg)
        v0 = __hip_atomic_load(&sb[i0], __ATOMIC_RELAXED, __HIP_MEMORY_SCOPE_AGENT);
      while ((unsigned)(v1 >> 32) != tg)
        v1 = __hip_atomic_load(&sb[i1], __ATOMIC_RELAXED, __HIP_MEMORY_SCOPE_AGENT);
      h_lds[p0] = __uint_as_float((unsigned)v0);
      h_lds[p1] = __uint_as_float((unsigned)v1);
      __syncthreads();
    }

    float acc0 = 0.f, acc1 = 0.f, acc2 = 0.f, acc3 = 0.f;
    const float* hseg = h_lds + s*HSTRIDE;
    #pragma unroll
    for (int c2 = 0; c2 < 16; ++c2) {
      float2 hv = *(const float2*)(hseg + 2*c2);
      acc0 = fmaf(w[0*32+2*c2], hv.x, acc0); acc0 = fmaf(w[0*32+2*c2+1], hv.y, acc0);
      acc1 = fmaf(w[1*32+2*c2], hv.x, acc1); acc1 = fmaf(w[1*32+2*c2+1], hv.y, acc1);
      acc2 = fmaf(w[2*32+2*c2], hv.x, acc2); acc2 = fmaf(w[2*32+2*c2+1], hv.y, acc2);
      acc3 = fmaf(w[3*32+2*c2], hv.x, acc3); acc3 = fmaf(w[3*32+2*c2+1], hv.y, acc3);
    }
    #pragma unroll
    for (int m = 1; m <= 16; m <<= 1) {
      acc0 += __shfl_xor(acc0, m);
      acc1 += __shfl_xor(acc1, m);
      acc2 += __shfl_xor(acc2, m);
      acc3 += __shfl_xor(acc3, m);
    }
    if (s < 4) {
      float v = acc0;
      if (s == 1) v = acc1; else if (s == 2) v = acc2; else if (s == 3) v = acc3;
      gates_lds[rg*4 + s] = v + gxv;
    }
    __syncthreads();

    if (tid < 8) {
      int n0 = tid*2, n1 = n0 + 1;
      float xi0 = gates_lds[n0],    xi1 = gates_lds[n1];
      float xf0 = gates_lds[16+n0], xf1 = gates_lds[16+n1];
      float xg0 = gates_lds[32+n0], xg1 = gates_lds[32+n1];
      float xo0 = gates_lds[48+n0], xo1 = gates_lds[48+n1];
      c0 = sigm(xf0)*c0 + sigm(xi0)*tanhf(xg0);
      c1 = sigm(xf1)*c1 + sigm(xi1)*tanhf(xg1);
      float h0 = sigm(xo0)*tanhf(c0);
      float h1 = sigm(xo1)*tanhf(c1);
      if (t == TT-1) {
        out[(b<<4)+n0]      = h0;       // fp32 output
        out[(b<<4)+n1]      = h1;
        out[1024+(b<<4)+n0] = c0;
        out[1024+(b<<4)+n1] = c1;
      } else {
        unsigned long long* db = slots + (size_t)((t+1)&1)*1024;
        unsigned long long tg = ((unsigned long long)(unsigned)(t+1)) << 32;
        __hip_atomic_store(&db[(b<<4)+n0], tg | (unsigned long long)__float_as_uint(h0),
                           __ATOMIC_RELAXED, __HIP_MEMORY_SCOPE_AGENT);
        __hip_atomic_store(&db[(b<<4)+n1], tg | (unsigned long long)__float_as_uint(h1),
                           __ATOMIC_RELAXED, __HIP_MEMORY_SCOPE_AGENT);
      }
    }
  }
}

// fallback: ws too small -> zeros
__global__ void zero_out(float* out){
  int i = blockIdx.x*256 + threadIdx.x;
  if (i < 2048) out[i] = 0.0f;
}

extern "C" void kernel_launch(void* const* d_in, const int* in_sizes, int n_in,
                              void* d_out, int out_size, void* d_ws, size_t ws_size,
                              hipStream_t stream) {
  (void)in_sizes; (void)n_in; (void)out_size;
  const int* tokens = (const int*)d_in[0];
  const float* emb  = (const float*)d_in[1];
  const float* Wih  = (const float*)d_in[2];
  const float* Whh  = (const float*)d_in[3];
  const float* bih  = (const float*)d_in[4];
  const float* bhh  = (const float*)d_in[5];
  float* out = (float*)d_out;     // reference output dtype = float32

  // ws: [0,16K) slots[2][1024] u64 | [16K, ...) gx fp32 [2048][4096]
  unsigned long long* slots = (unsigned long long*)d_ws;
  float* gx = (float*)((char*)d_ws + 16384);
  const size_t needF32 = 16384 + (size_t)TT*GH*sizeof(float);

  hipMemsetAsync(slots, 0, 16384, stream);
  if (ws_size >= needF32) {
    gemm_simple<<<dim3(64,16), dim3(256), 0, stream>>>(tokens, emb, Wih, bih, bhh, gx);
    lstm_scan<<<dim3(GBLK), dim3(NTH), 0, stream>>>(gx, Whh, slots, out);
  } else {
    zero_out<<<dim3(8), dim3(256), 0, stream>>>(out);
  }
}